// Round 1
// baseline (2313.625 us; speedup 1.0000x reference)
//
#include <hip/hip_runtime.h>

#define NN 100000
#define DD 128
#define EE 600000
#define LNEPS 1e-5f

__device__ __forceinline__ float lrelu(float v) { return v > 0.f ? v : 0.2f * v; }

// ---------------- lin: xl = x@wl+bl, xr = x@wr+br  (N x 128 @ 128 x 128, two weights)
__global__ __launch_bounds__(256) void lin_kernel(
    const float* __restrict__ x,
    const float* __restrict__ wl, const float* __restrict__ bl,
    const float* __restrict__ wr, const float* __restrict__ br,
    float* __restrict__ xl, float* __restrict__ xr)
{
    __shared__ __align__(16) float xs[64][128];
    const int tid  = threadIdx.x;
    const int row0 = blockIdx.x * 64;
#pragma unroll
    for (int i = 0; i < 32; ++i) {
        int idx = tid + i * 256;
        int r = idx >> 7, c = idx & 127;
        int row = row0 + r;
        xs[r][c] = (row < NN) ? x[(size_t)row * DD + c] : 0.f;
    }
    __syncthreads();
    const int cg = tid & 63;   // column in [0,64): computes cols cg, cg+64 of both outputs
    const int rg = tid >> 6;   // row group: rows rg*16 .. rg*16+15
    float acc[16][4];
    {
        float b0 = bl[cg], b1 = bl[cg + 64], b2 = br[cg], b3 = br[cg + 64];
#pragma unroll
        for (int r = 0; r < 16; ++r) { acc[r][0] = b0; acc[r][1] = b1; acc[r][2] = b2; acc[r][3] = b3; }
    }
    for (int k = 0; k < 128; k += 4) {
        float wa[4], wb[4], wc[4], wd[4];
#pragma unroll
        for (int i = 0; i < 4; ++i) {
            wa[i] = wl[(k + i) * DD + cg];
            wb[i] = wl[(k + i) * DD + cg + 64];
            wc[i] = wr[(k + i) * DD + cg];
            wd[i] = wr[(k + i) * DD + cg + 64];
        }
#pragma unroll
        for (int r = 0; r < 16; ++r) {
            float4 xv = *(const float4*)&xs[rg * 16 + r][k];
            acc[r][0] = fmaf(xv.x, wa[0], fmaf(xv.y, wa[1], fmaf(xv.z, wa[2], fmaf(xv.w, wa[3], acc[r][0]))));
            acc[r][1] = fmaf(xv.x, wb[0], fmaf(xv.y, wb[1], fmaf(xv.z, wb[2], fmaf(xv.w, wb[3], acc[r][1]))));
            acc[r][2] = fmaf(xv.x, wc[0], fmaf(xv.y, wc[1], fmaf(xv.z, wc[2], fmaf(xv.w, wc[3], acc[r][2]))));
            acc[r][3] = fmaf(xv.x, wd[0], fmaf(xv.y, wd[1], fmaf(xv.z, wd[2], fmaf(xv.w, wd[3], acc[r][3]))));
        }
    }
#pragma unroll
    for (int r = 0; r < 16; ++r) {
        int row = row0 + rg * 16 + r;
        if (row < NN) {
            xl[(size_t)row * DD + cg]      = acc[r][0];
            xl[(size_t)row * DD + cg + 64] = acc[r][1];
            xr[(size_t)row * DD + cg]      = acc[r][2];
            xr[(size_t)row * DD + cg + 64] = acc[r][3];
        }
    }
}

// ---------------- edge pass 1: ex[e,h] = exp(alpha), denom[dst,h] += ex
// one wave per edge; lane covers elems lane*2, lane*2+1 (head = lane>>4)
__global__ __launch_bounds__(256) void edge_alpha_kernel(
    const float* __restrict__ xl, const float* __restrict__ xr,
    const int* __restrict__ ei, const float* __restrict__ att,
    float* __restrict__ ex, float* __restrict__ denom)
{
    int e = blockIdx.x * 4 + (threadIdx.x >> 6);
    if (e >= EE) return;
    int lane = threadIdx.x & 63;
    int src = ei[e], dst = ei[EE + e];
    float2 xlv = *(const float2*)&xl[(size_t)src * DD + lane * 2];
    float2 xrv = *(const float2*)&xr[(size_t)dst * DD + lane * 2];
    float2 av  = *(const float2*)&att[lane * 2];
    float p = lrelu(xlv.x + xrv.x) * av.x + lrelu(xlv.y + xrv.y) * av.y;
#pragma unroll
    for (int m = 1; m < 16; m <<= 1) p += __shfl_xor(p, m);
    if ((lane & 15) == 0) {
        int h = lane >> 4;
        float exv = __expf(p);           // max-shift skipped: |alpha| << 88, identical softmax
        ex[(size_t)e * 4 + h] = exv;
        unsafeAtomicAdd(&denom[(size_t)dst * 4 + h], exv);
    }
}

// ---------------- edge pass 2: hacc[dst] += xl[src] * a
__global__ __launch_bounds__(256) void edge_scatter_kernel(
    const float* __restrict__ xl, const int* __restrict__ ei,
    const float* __restrict__ ex, const float* __restrict__ denom,
    float* __restrict__ hacc)
{
    int e = blockIdx.x * 4 + (threadIdx.x >> 6);
    if (e >= EE) return;
    int lane = threadIdx.x & 63;
    int src = ei[e], dst = ei[EE + e];
    int h = lane >> 4;
    float a = ex[(size_t)e * 4 + h] / (denom[(size_t)dst * 4 + h] + 1e-16f);
    float2 xlv = *(const float2*)&xl[(size_t)src * DD + lane * 2];
    unsafeAtomicAdd(&hacc[(size_t)dst * DD + lane * 2],     xlv.x * a);
    unsafeAtomicAdd(&hacc[(size_t)dst * DD + lane * 2 + 1], xlv.y * a);
}

// ---------------- fused: h = hacc + cbias; out = LN(h + relu(h@w1+b1)@w2 + b2)
__global__ __launch_bounds__(256) void ffn_ln_kernel(
    const float* __restrict__ hacc, const float* __restrict__ cbias,
    const float* __restrict__ w1, const float* __restrict__ b1,
    const float* __restrict__ w2, const float* __restrict__ b2,
    const float* __restrict__ g, const float* __restrict__ bb,
    float* __restrict__ out)
{
    __shared__ __align__(16) float hrow[16][128];
    __shared__ __align__(16) float T[16][512];
    __shared__ __align__(16) float ybuf[16][128];
    const int tid  = threadIdx.x;
    const int row0 = blockIdx.x * 16;    // N % 16 == 0, no guard needed
#pragma unroll
    for (int i = 0; i < 8; ++i) {
        int idx = tid + i * 256;
        int r = idx >> 7, c = idx & 127;
        hrow[r][c] = hacc[(size_t)(row0 + r) * DD + c] + cbias[c];
    }
    __syncthreads();
    // phase 1: T = relu(hrow @ w1 + b1); thread owns cols f, f+256 for all 16 rows
    {
        const int f = tid;
        float acc[16][2];
        float ba = b1[f], bcol = b1[f + 256];
#pragma unroll
        for (int r = 0; r < 16; ++r) { acc[r][0] = ba; acc[r][1] = bcol; }
        for (int k = 0; k < 128; k += 4) {
            float wa[4], wb[4];
#pragma unroll
            for (int i = 0; i < 4; ++i) { wa[i] = w1[(k + i) * 512 + f]; wb[i] = w1[(k + i) * 512 + f + 256]; }
#pragma unroll
            for (int r = 0; r < 16; ++r) {
                float4 xv = *(const float4*)&hrow[r][k];
                acc[r][0] = fmaf(xv.x, wa[0], fmaf(xv.y, wa[1], fmaf(xv.z, wa[2], fmaf(xv.w, wa[3], acc[r][0]))));
                acc[r][1] = fmaf(xv.x, wb[0], fmaf(xv.y, wb[1], fmaf(xv.z, wb[2], fmaf(xv.w, wb[3], acc[r][1]))));
            }
        }
#pragma unroll
        for (int r = 0; r < 16; ++r) {
            T[r][f]       = fmaxf(acc[r][0], 0.f);
            T[r][f + 256] = fmaxf(acc[r][1], 0.f);
        }
    }
    __syncthreads();
    // phase 2: y = T @ w2 (+b2 + residual); thread = (col d, k-half)
    {
        const int d  = tid & 127;
        const int kh = tid >> 7;
        float acc[16];
#pragma unroll
        for (int r = 0; r < 16; ++r) acc[r] = 0.f;
        const int k0 = kh * 256;
        for (int k = k0; k < k0 + 256; k += 4) {
            float wv[4];
#pragma unroll
            for (int i = 0; i < 4; ++i) wv[i] = w2[(k + i) * DD + d];
#pragma unroll
            for (int r = 0; r < 16; ++r) {
                float4 tv = *(const float4*)&T[r][k];
                acc[r] = fmaf(tv.x, wv[0], fmaf(tv.y, wv[1], fmaf(tv.z, wv[2], fmaf(tv.w, wv[3], acc[r]))));
            }
        }
        if (kh == 1) {
#pragma unroll
            for (int r = 0; r < 16; ++r) ybuf[r][d] = acc[r];
        }
        __syncthreads();
        if (kh == 0) {
            float bv = b2[d];
#pragma unroll
            for (int r = 0; r < 16; ++r)
                ybuf[r][d] = acc[r] + ybuf[r][d] + bv + hrow[r][d];
        }
    }
    __syncthreads();
    // LN: wave w handles rows w, w+4, w+8, w+12
    {
        const int wv = tid >> 6, lane = tid & 63;
        for (int r = wv; r < 16; r += 4) {
            float2 yv = *(const float2*)&ybuf[r][lane * 2];
            float s  = yv.x + yv.y;
            float s2 = yv.x * yv.x + yv.y * yv.y;
#pragma unroll
            for (int m = 1; m < 64; m <<= 1) { s += __shfl_xor(s, m); s2 += __shfl_xor(s2, m); }
            float mu  = s * (1.f / 128.f);
            float var = s2 * (1.f / 128.f) - mu * mu;
            float inv = rsqrtf(var + LNEPS);
            float2 gv = *(const float2*)&g[lane * 2];
            float2 bv = *(const float2*)&bb[lane * 2];
            float2 o;
            o.x = (yv.x - mu) * inv * gv.x + bv.x;
            o.y = (yv.y - mu) * inv * gv.y + bv.y;
            *(float2*)&out[(size_t)(row0 + r) * DD + lane * 2] = o;
        }
    }
}

extern "C" void kernel_launch(void* const* d_in, const int* in_sizes, int n_in,
                              void* d_out, int out_size, void* d_ws, size_t ws_size,
                              hipStream_t stream)
{
    const float* x       = (const float*)d_in[0];
    const int*   ei      = (const int*)d_in[1];
    const float* c1_wl   = (const float*)d_in[2];
    const float* c1_bl   = (const float*)d_in[3];
    const float* c1_wr   = (const float*)d_in[4];
    const float* c1_br   = (const float*)d_in[5];
    const float* c1_att  = (const float*)d_in[6];
    const float* c1_bias = (const float*)d_in[7];
    const float* c2_wl   = (const float*)d_in[8];
    const float* c2_bl   = (const float*)d_in[9];
    const float* c2_wr   = (const float*)d_in[10];
    const float* c2_br   = (const float*)d_in[11];
    const float* c2_att  = (const float*)d_in[12];
    const float* c2_bias = (const float*)d_in[13];
    const float* f1_w1   = (const float*)d_in[14];
    const float* f1_b1   = (const float*)d_in[15];
    const float* f1_w2   = (const float*)d_in[16];
    const float* f1_b2   = (const float*)d_in[17];
    const float* f2_w1   = (const float*)d_in[18];
    const float* f2_b1   = (const float*)d_in[19];
    const float* f2_w2   = (const float*)d_in[20];
    const float* f2_b2   = (const float*)d_in[21];
    const float* ln1_g   = (const float*)d_in[22];
    const float* ln1_b   = (const float*)d_in[23];
    const float* ln2_g   = (const float*)d_in[24];
    const float* ln2_b   = (const float*)d_in[25];

    float* out = (float*)d_out;
    float* ws  = (float*)d_ws;
    float* xl    = ws;                                  // N*128
    float* xr    = xl   + (size_t)NN * DD;              // N*128
    float* hacc  = xr   + (size_t)NN * DD;              // N*128
    float* ex    = hacc + (size_t)NN * DD;              // E*4
    float* denom = ex   + (size_t)EE * 4;               // N*4

    const dim3 blk(256);
    const int linGrid  = (NN + 63) / 64;
    const int edgeGrid = (EE + 3) / 4;
    const int ffnGrid  = NN / 16;

    // ---------- layer 1 ----------
    hipMemsetAsync(hacc, 0, (size_t)NN * DD * sizeof(float), stream);
    hipMemsetAsync(denom, 0, (size_t)NN * 4 * sizeof(float), stream);
    lin_kernel<<<linGrid, blk, 0, stream>>>(x, c1_wl, c1_bl, c1_wr, c1_br, xl, xr);
    edge_alpha_kernel<<<edgeGrid, blk, 0, stream>>>(xl, xr, ei, c1_att, ex, denom);
    edge_scatter_kernel<<<edgeGrid, blk, 0, stream>>>(xl, ei, ex, denom, hacc);
    ffn_ln_kernel<<<ffnGrid, blk, 0, stream>>>(hacc, c1_bias, f1_w1, f1_b1, f1_w2, f1_b2,
                                               ln1_g, ln1_b, out);
    // ---------- layer 2 ----------
    hipMemsetAsync(hacc, 0, (size_t)NN * DD * sizeof(float), stream);
    hipMemsetAsync(denom, 0, (size_t)NN * 4 * sizeof(float), stream);
    lin_kernel<<<linGrid, blk, 0, stream>>>(out, c2_wl, c2_bl, c2_wr, c2_br, xl, xr);
    edge_alpha_kernel<<<edgeGrid, blk, 0, stream>>>(xl, xr, ei, c2_att, ex, denom);
    edge_scatter_kernel<<<edgeGrid, blk, 0, stream>>>(xl, ei, ex, denom, hacc);
    ffn_ln_kernel<<<ffnGrid, blk, 0, stream>>>(hacc, c2_bias, f2_w1, f2_b1, f2_w2, f2_b2,
                                               ln2_g, ln2_b, out);
}

// Round 2
// 1336.486 us; speedup vs baseline: 1.7311x; 1.7311x over previous
//
#include <hip/hip_runtime.h>

#define NN 100000
#define DD 128
#define EE 600000
#define LNEPS 1e-5f

__device__ __forceinline__ float lrelu(float v) { return v > 0.f ? v : 0.2f * v; }

// ---------------- lin: xl = x@wl+bl, xr = x@wr+br  (N x 128 @ 128 x 128, two weights)
__global__ __launch_bounds__(256) void lin_kernel(
    const float* __restrict__ x,
    const float* __restrict__ wl, const float* __restrict__ bl,
    const float* __restrict__ wr, const float* __restrict__ br,
    float* __restrict__ xl, float* __restrict__ xr)
{
    __shared__ __align__(16) float xs[64][128];
    const int tid  = threadIdx.x;
    const int row0 = blockIdx.x * 64;
#pragma unroll
    for (int i = 0; i < 32; ++i) {
        int idx = tid + i * 256;
        int r = idx >> 7, c = idx & 127;
        int row = row0 + r;
        xs[r][c] = (row < NN) ? x[(size_t)row * DD + c] : 0.f;
    }
    __syncthreads();
    const int cg = tid & 63;
    const int rg = tid >> 6;
    float acc[16][4];
    {
        float b0 = bl[cg], b1 = bl[cg + 64], b2 = br[cg], b3 = br[cg + 64];
#pragma unroll
        for (int r = 0; r < 16; ++r) { acc[r][0] = b0; acc[r][1] = b1; acc[r][2] = b2; acc[r][3] = b3; }
    }
    for (int k = 0; k < 128; k += 4) {
        float wa[4], wb[4], wc[4], wd[4];
#pragma unroll
        for (int i = 0; i < 4; ++i) {
            wa[i] = wl[(k + i) * DD + cg];
            wb[i] = wl[(k + i) * DD + cg + 64];
            wc[i] = wr[(k + i) * DD + cg];
            wd[i] = wr[(k + i) * DD + cg + 64];
        }
#pragma unroll
        for (int r = 0; r < 16; ++r) {
            float4 xv = *(const float4*)&xs[rg * 16 + r][k];
            acc[r][0] = fmaf(xv.x, wa[0], fmaf(xv.y, wa[1], fmaf(xv.z, wa[2], fmaf(xv.w, wa[3], acc[r][0]))));
            acc[r][1] = fmaf(xv.x, wb[0], fmaf(xv.y, wb[1], fmaf(xv.z, wb[2], fmaf(xv.w, wb[3], acc[r][1]))));
            acc[r][2] = fmaf(xv.x, wc[0], fmaf(xv.y, wc[1], fmaf(xv.z, wc[2], fmaf(xv.w, wc[3], acc[r][2]))));
            acc[r][3] = fmaf(xv.x, wd[0], fmaf(xv.y, wd[1], fmaf(xv.z, wd[2], fmaf(xv.w, wd[3], acc[r][3]))));
        }
    }
#pragma unroll
    for (int r = 0; r < 16; ++r) {
        int row = row0 + rg * 16 + r;
        if (row < NN) {
            xl[(size_t)row * DD + cg]      = acc[r][0];
            xl[(size_t)row * DD + cg + 64] = acc[r][1];
            xr[(size_t)row * DD + cg]      = acc[r][2];
            xr[(size_t)row * DD + cg + 64] = acc[r][3];
        }
    }
}

// ---------------- CSR build ----------------
__global__ __launch_bounds__(256) void deg_hist_kernel(const int* __restrict__ ei, int* __restrict__ deg)
{
    int e = blockIdx.x * 256 + threadIdx.x;
    if (e < EE) atomicAdd(&deg[ei[EE + e]], 1);
}

// block = 1024, each thread one element; exclusive scan per block + partials
__global__ __launch_bounds__(1024) void scan1_kernel(const int* __restrict__ deg,
                                                     int* __restrict__ rowstart,
                                                     int* __restrict__ partials)
{
    int gid = blockIdx.x * 1024 + threadIdx.x;
    int v = (gid < NN) ? deg[gid] : 0;
    int lane = threadIdx.x & 63, wid = threadIdx.x >> 6;
    int s = v;
#pragma unroll
    for (int o = 1; o < 64; o <<= 1) { int t = __shfl_up(s, o); if (lane >= o) s += t; }
    __shared__ int wsum[16];
    if (lane == 63) wsum[wid] = s;
    __syncthreads();
    if (wid == 0 && lane < 16) {
        int w = wsum[lane];
        int ws = w;
#pragma unroll
        for (int o = 1; o < 16; o <<= 1) { int t = __shfl_up(ws, o); if (lane >= o) ws += t; }
        wsum[lane] = ws - w;   // exclusive wave offset
    }
    __syncthreads();
    int incl = s + wsum[wid];
    if (gid < NN) rowstart[gid] = incl - v;
    if (threadIdx.x == 1023) partials[blockIdx.x] = incl;
}

// single block, 128 threads, exclusive scan of nb (<=128) partials in place
__global__ __launch_bounds__(128) void scan2_kernel(int* __restrict__ partials, int nb)
{
    int t = threadIdx.x;
    int v = (t < nb) ? partials[t] : 0;
    int lane = t & 63, wid = t >> 6;
    int s = v;
#pragma unroll
    for (int o = 1; o < 64; o <<= 1) { int tt = __shfl_up(s, o); if (lane >= o) s += tt; }
    __shared__ int wsum[2];
    if (lane == 63) wsum[wid] = s;
    __syncthreads();
    int add = (wid == 1) ? wsum[0] : 0;
    if (t < nb) partials[t] = s + add - v;
}

__global__ __launch_bounds__(1024) void scan3_kernel(int* __restrict__ rowstart, const int* __restrict__ partials)
{
    int gid = blockIdx.x * 1024 + threadIdx.x;
    if (gid < NN) rowstart[gid] += partials[blockIdx.x];
}

__global__ __launch_bounds__(256) void fill_kernel(const int* __restrict__ ei,
                                                   int* __restrict__ cursor,
                                                   int* __restrict__ esrc)
{
    int e = blockIdx.x * 256 + threadIdx.x;
    if (e >= EE) return;
    int dst = ei[EE + e];
    int pos = atomicAdd(&cursor[dst], 1);
    esrc[pos] = ei[e];
}

// ---------------- gather: per dst node, fused alpha + softmax + weighted sum
// one wave per node; lane covers elems lane*2, lane*2+1 (head = lane>>4)
__global__ __launch_bounds__(256) void gather_kernel(
    const float* __restrict__ xl, const float* __restrict__ xr,
    const int* __restrict__ esrc,
    const int* __restrict__ rowstart, const int* __restrict__ rowend,
    const float* __restrict__ att,
    float* __restrict__ hacc)
{
    int n = blockIdx.x * 4 + (threadIdx.x >> 6);
    if (n >= NN) return;
    int lane = threadIdx.x & 63;
    float2 xrv = *(const float2*)&xr[(size_t)n * DD + lane * 2];
    float2 av  = *(const float2*)&att[lane * 2];
    int s0 = rowstart[n], s1 = rowend[n];
    float accx = 0.f, accy = 0.f, denom = 0.f;
    for (int j = s0; j < s1; ++j) {
        int src = esrc[j];
        float2 xlv = *(const float2*)&xl[(size_t)src * DD + lane * 2];
        float p = lrelu(xlv.x + xrv.x) * av.x + lrelu(xlv.y + xrv.y) * av.y;
#pragma unroll
        for (int m = 1; m < 16; m <<= 1) p += __shfl_xor(p, m);
        float exv = __expf(p);     // max-shift skipped: |alpha| << 88, softmax identical
        denom += exv;
        accx = fmaf(exv, xlv.x, accx);
        accy = fmaf(exv, xlv.y, accy);
    }
    float inv = 1.f / (denom + 1e-16f);
    float2 o; o.x = accx * inv; o.y = accy * inv;
    *(float2*)&hacc[(size_t)n * DD + lane * 2] = o;
}

// ---------------- fused: h = hacc + cbias; out = LN(h + relu(h@w1+b1)@w2 + b2)
__global__ __launch_bounds__(256) void ffn_ln_kernel(
    const float* __restrict__ hacc, const float* __restrict__ cbias,
    const float* __restrict__ w1, const float* __restrict__ b1,
    const float* __restrict__ w2, const float* __restrict__ b2,
    const float* __restrict__ g, const float* __restrict__ bb,
    float* __restrict__ out)
{
    __shared__ __align__(16) float hrow[16][128];
    __shared__ __align__(16) float T[16][512];
    __shared__ __align__(16) float ybuf[16][128];
    const int tid  = threadIdx.x;
    const int row0 = blockIdx.x * 16;
#pragma unroll
    for (int i = 0; i < 8; ++i) {
        int idx = tid + i * 256;
        int r = idx >> 7, c = idx & 127;
        hrow[r][c] = hacc[(size_t)(row0 + r) * DD + c] + cbias[c];
    }
    __syncthreads();
    {
        const int f = tid;
        float acc[16][2];
        float ba = b1[f], bcol = b1[f + 256];
#pragma unroll
        for (int r = 0; r < 16; ++r) { acc[r][0] = ba; acc[r][1] = bcol; }
        for (int k = 0; k < 128; k += 4) {
            float wa[4], wb[4];
#pragma unroll
            for (int i = 0; i < 4; ++i) { wa[i] = w1[(k + i) * 512 + f]; wb[i] = w1[(k + i) * 512 + f + 256]; }
#pragma unroll
            for (int r = 0; r < 16; ++r) {
                float4 xv = *(const float4*)&hrow[r][k];
                acc[r][0] = fmaf(xv.x, wa[0], fmaf(xv.y, wa[1], fmaf(xv.z, wa[2], fmaf(xv.w, wa[3], acc[r][0]))));
                acc[r][1] = fmaf(xv.x, wb[0], fmaf(xv.y, wb[1], fmaf(xv.z, wb[2], fmaf(xv.w, wb[3], acc[r][1]))));
            }
        }
#pragma unroll
        for (int r = 0; r < 16; ++r) {
            T[r][f]       = fmaxf(acc[r][0], 0.f);
            T[r][f + 256] = fmaxf(acc[r][1], 0.f);
        }
    }
    __syncthreads();
    {
        const int d  = tid & 127;
        const int kh = tid >> 7;
        float acc[16];
#pragma unroll
        for (int r = 0; r < 16; ++r) acc[r] = 0.f;
        const int k0 = kh * 256;
        for (int k = k0; k < k0 + 256; k += 4) {
            float wv[4];
#pragma unroll
            for (int i = 0; i < 4; ++i) wv[i] = w2[(k + i) * DD + d];
#pragma unroll
            for (int r = 0; r < 16; ++r) {
                float4 tv = *(const float4*)&T[r][k];
                acc[r] = fmaf(tv.x, wv[0], fmaf(tv.y, wv[1], fmaf(tv.z, wv[2], fmaf(tv.w, wv[3], acc[r]))));
            }
        }
        if (kh == 1) {
#pragma unroll
            for (int r = 0; r < 16; ++r) ybuf[r][d] = acc[r];
        }
        __syncthreads();
        if (kh == 0) {
            float bv = b2[d];
#pragma unroll
            for (int r = 0; r < 16; ++r)
                ybuf[r][d] = acc[r] + ybuf[r][d] + bv + hrow[r][d];
        }
    }
    __syncthreads();
    {
        const int wv = tid >> 6, lane = tid & 63;
        for (int r = wv; r < 16; r += 4) {
            float2 yv = *(const float2*)&ybuf[r][lane * 2];
            float s  = yv.x + yv.y;
            float s2 = yv.x * yv.x + yv.y * yv.y;
#pragma unroll
            for (int m = 1; m < 64; m <<= 1) { s += __shfl_xor(s, m); s2 += __shfl_xor(s2, m); }
            float mu  = s * (1.f / 128.f);
            float var = s2 * (1.f / 128.f) - mu * mu;
            float inv = rsqrtf(var + LNEPS);
            float2 gv = *(const float2*)&g[lane * 2];
            float2 bv = *(const float2*)&bb[lane * 2];
            float2 o;
            o.x = (yv.x - mu) * inv * gv.x + bv.x;
            o.y = (yv.y - mu) * inv * gv.y + bv.y;
            *(float2*)&out[(size_t)(row0 + r) * DD + lane * 2] = o;
        }
    }
}

extern "C" void kernel_launch(void* const* d_in, const int* in_sizes, int n_in,
                              void* d_out, int out_size, void* d_ws, size_t ws_size,
                              hipStream_t stream)
{
    const float* x       = (const float*)d_in[0];
    const int*   ei      = (const int*)d_in[1];
    const float* c1_wl   = (const float*)d_in[2];
    const float* c1_bl   = (const float*)d_in[3];
    const float* c1_wr   = (const float*)d_in[4];
    const float* c1_br   = (const float*)d_in[5];
    const float* c1_att  = (const float*)d_in[6];
    const float* c1_bias = (const float*)d_in[7];
    const float* c2_wl   = (const float*)d_in[8];
    const float* c2_bl   = (const float*)d_in[9];
    const float* c2_wr   = (const float*)d_in[10];
    const float* c2_br   = (const float*)d_in[11];
    const float* c2_att  = (const float*)d_in[12];
    const float* c2_bias = (const float*)d_in[13];
    const float* f1_w1   = (const float*)d_in[14];
    const float* f1_b1   = (const float*)d_in[15];
    const float* f1_w2   = (const float*)d_in[16];
    const float* f1_b2   = (const float*)d_in[17];
    const float* f2_w1   = (const float*)d_in[18];
    const float* f2_b1   = (const float*)d_in[19];
    const float* f2_w2   = (const float*)d_in[20];
    const float* f2_b2   = (const float*)d_in[21];
    const float* ln1_g   = (const float*)d_in[22];
    const float* ln1_b   = (const float*)d_in[23];
    const float* ln2_g   = (const float*)d_in[24];
    const float* ln2_b   = (const float*)d_in[25];

    float* out = (float*)d_out;
    float* ws  = (float*)d_ws;
    float* xl    = ws;                                  // N*128 f32
    float* xr    = xl   + (size_t)NN * DD;              // N*128 f32
    float* hacc  = xr   + (size_t)NN * DD;              // N*128 f32
    int* deg      = (int*)(hacc + (size_t)NN * DD);     // N
    int* rowstart = deg + NN;                           // N
    int* cursor   = rowstart + NN;                      // N
    int* partials = cursor + NN;                        // 128
    int* esrc     = partials + 128;                     // E

    const dim3 blk(256);
    const int linGrid    = (NN + 63) / 64;
    const int edgeGrid   = (EE + 255) / 256;
    const int gatherGrid = (NN + 3) / 4;
    const int ffnGrid    = NN / 16;
    const int scanBlocks = (NN + 1023) / 1024;          // 98

    // ---------- CSR build (edge structure shared by both layers) ----------
    hipMemsetAsync(deg, 0, (size_t)NN * sizeof(int), stream);
    deg_hist_kernel<<<edgeGrid, blk, 0, stream>>>(ei, deg);
    scan1_kernel<<<scanBlocks, 1024, 0, stream>>>(deg, rowstart, partials);
    scan2_kernel<<<1, 128, 0, stream>>>(partials, scanBlocks);
    scan3_kernel<<<scanBlocks, 1024, 0, stream>>>(rowstart, partials);
    hipMemcpyAsync(cursor, rowstart, (size_t)NN * sizeof(int), hipMemcpyDeviceToDevice, stream);
    fill_kernel<<<edgeGrid, blk, 0, stream>>>(ei, cursor, esrc);
    // after fill: cursor[n] == rowstart[n] + deg[n] == row end

    // ---------- layer 1 ----------
    lin_kernel<<<linGrid, blk, 0, stream>>>(x, c1_wl, c1_bl, c1_wr, c1_br, xl, xr);
    gather_kernel<<<gatherGrid, blk, 0, stream>>>(xl, xr, esrc, rowstart, cursor, c1_att, hacc);
    ffn_ln_kernel<<<ffnGrid, blk, 0, stream>>>(hacc, c1_bias, f1_w1, f1_b1, f1_w2, f1_b2,
                                               ln1_g, ln1_b, out);
    // ---------- layer 2 ----------
    lin_kernel<<<linGrid, blk, 0, stream>>>(out, c2_wl, c2_bl, c2_wr, c2_br, xl, xr);
    gather_kernel<<<gatherGrid, blk, 0, stream>>>(xl, xr, esrc, rowstart, cursor, c2_att, hacc);
    ffn_ln_kernel<<<ffnGrid, blk, 0, stream>>>(hacc, c2_bias, f2_w1, f2_b1, f2_w2, f2_b2,
                                               ln2_g, ln2_b, out);
}